// Round 7
// baseline (397.051 us; speedup 1.0000x reference)
//
#include <hip/hip_runtime.h>
#include <cstdint>
#include <cstddef>

// Binarized basic block on MI355X.
// |acc| <= 9*128 = 1152 < THRESH=8000, so the per-partial-sum clip never
// binds -> both convs are exact int convolutions of sign() values.
// int8 implicit GEMM via mfma_i32_16x16x64_i8; all float ops bit-exact vs
// numpy fp32 (explicit __fmul_rn/__fadd_rn, no FMA contraction).
//
// R7: R6 was latency-bound (MfmaUtil 12%): every wave read ALL 128 O's
// B-frags from LDS (64 KB/CU-step ~770cyc > 652cyc MFMA/SIMD-step).
// Now 8 waves = 4 row-quarters x 2 O-HALVES: wave = 64 rows x 64 O,
// per step 4 ds_read_b128 + 16 MFMA -> LDS 32 KB/CU-step (~385cyc) vs
// MFMA 652cyc/SIMD-step -> matrix-bound with 1.7x margin. acc[4][4]=64
// VGPRs; K-loop stays unroll-1 (R6's fix for the 256-VGPR spill).
// O-mapping o = half*64 + l15*4 + nl (4 contiguous ch/lane -> full-line
// 64B stores). Weights stay fully LDS-resident; XCD-local tiles.

typedef int      v4i __attribute__((ext_vector_type(4)));
typedef float    v4f __attribute__((ext_vector_type(4)));

constexpr int B = 64, C = 128, H = 56, W = 56;
constexpr int HP = H + 2, WP = W + 2;      // zero-padded spatial
constexpr int PIX = H * W;                 // 3136
constexpr int M = B * H * W;               // 200704 = 784 * 256
constexpr int NTILES = M / 256;            // 784 tiles of 256 rows
constexpr int TPX = NTILES / 8;            // 98 tiles per XCD

// workspace layout (bytes)
constexpr size_t XS_BYTES = (size_t)B * HP * WP * C;   // 27,557,888
constexpr size_t XS1_OFF = 0;
constexpr size_t XS2_OFF = XS_BYTES;
constexpr size_t WF_BYTES = 18 * 8192;                 // 147,456
constexpr size_t WF1_OFF = 2 * XS_BYTES;
constexpr size_t WF2_OFF = WF1_OFF + WF_BYTES;
constexpr size_t BNP_OFF = WF2_OFF + WF_BYTES;         // 4*128 floats

// ---------------------------------------------------------------------------
// Zero only the padded halos of xs1/xs2 (interiors are fully overwritten).
// 256 blocks: 4 blocks per image.
__global__ __launch_bounds__(256) void zero_halo(int8_t* __restrict__ xs1,
                                                 int8_t* __restrict__ xs2) {
    int b = blockIdx.x >> 2;
    int q = blockIdx.x & 3;
    int t = q * 256 + threadIdx.x;           // 0..1023
    size_t ib = (size_t)b * HP * WP * C;
#pragma unroll
    for (int a = 0; a < 2; ++a) {
        uint32_t* p = (uint32_t*)((a ? xs2 : xs1) + ib);
        const int ROWD = WP * C / 4;             // 1856 dwords per padded row
        for (int i = t; i < ROWD; i += 1024) {
            p[i] = 0;
            p[(HP - 1) * ROWD + i] = 0;
        }
        for (int i = t; i < 56 * 2 * 32; i += 1024) {
            int r = i >> 6;
            int side = (i >> 5) & 1;
            int j = i & 31;
            p[((r + 1) * WP + side * (WP - 1)) * (C / 4) + j] = 0;
        }
    }
}

// ---------------------------------------------------------------------------
// sign(x) -> padded NHWC int8, via LDS transpose so global stores are
// 16 B/lane full-line. Block = 256 threads = 256 pixels.
__global__ __launch_bounds__(256) void prep_x(const float* __restrict__ x,
                                              int8_t* __restrict__ xs) {
    __shared__ uint32_t tl[256 * 33];   // +1 dword pad -> conflict-free
    int t = threadIdx.x;
    int m = blockIdx.x * 256 + t;
    int b_ = m / PIX, hw = m % PIX;
    const float* xp = x + (size_t)b_ * C * PIX + hw;
#pragma unroll
    for (int c4 = 0; c4 < 32; ++c4) {
        uint32_t v = 0;
#pragma unroll
        for (int j = 0; j < 4; ++j) {
            float f = xp[(size_t)(c4 * 4 + j) * PIX];
            v |= ((uint32_t)(uint8_t)(int8_t)((f > 0.f) - (f < 0.f))) << (8 * j);
        }
        tl[t * 33 + c4] = v;
    }
    __syncthreads();
    int pl = t >> 3, co = t & 7;        // 8 threads per pixel, 16 B each
#pragma unroll
    for (int pass = 0; pass < 8; ++pass) {
        int p = pass * 32 + pl;
        int mg = blockIdx.x * 256 + p;
        int b2 = mg / PIX, hw2 = mg % PIX, h2 = hw2 / W, w2 = hw2 % W;
        size_t ob = ((size_t)(b2 * HP + h2 + 1) * WP + (w2 + 1)) * C + co * 16;
        v4i val;
#pragma unroll
        for (int k = 0; k < 4; ++k) val[k] = (int)tl[p * 33 + co * 4 + k];
        *(v4i*)(xs + ob) = val;
    }
}

// ---------------------------------------------------------------------------
// Binarize weights into MFMA B-fragment order. Fragment tile j (0..7, 16 O
// each) at LDS offset j*1024; column col=lane&15 maps to output channel
//   o = (j>>2)*64 + (lane&15)*4 + (j&3)
// so a wave owning O-half (j>>2) with sub-tile nl=(j&3) gives each lane 4
// CONTIGUOUS channels. Also BN inv/shift tables exactly as numpy fp32.
__global__ __launch_bounds__(256) void prep_w(
    const float* __restrict__ w1, const float* __restrict__ w2,
    const float* __restrict__ g1, const float* __restrict__ be1,
    const float* __restrict__ mu1, const float* __restrict__ va1,
    const float* __restrict__ g2, const float* __restrict__ be2,
    const float* __restrict__ mu2, const float* __restrict__ va2,
    int8_t* __restrict__ wf1, int8_t* __restrict__ wf2,
    float* __restrict__ bnp) {
    int t = blockIdx.x * 256 + threadIdx.x;
    if (t < 256) {
        int o = t & 127;
        if (t < 128) {
            float inv = g1[o] / sqrtf(va1[o] + 1e-5f);
            bnp[o]       = inv;
            bnp[128 + o] = __fsub_rn(be1[o], __fmul_rn(mu1[o], inv));
        } else {
            float inv = g2[o] / sqrtf(va2[o] + 1e-5f);
            bnp[256 + o] = inv;
            bnp[384 + o] = __fsub_rn(be2[o], __fmul_rn(mu2[o], inv));
        }
    }
    if (t >= 2 * 18 * 8 * 64) return;
    int lane = t & 63;
    int j    = (t >> 6) & 7;
    int kh   = (t >> 9) & 1;
    int tap  = (t >> 10) % 9;
    int which = (t >> 10) / 9;
    const float* w = which ? w2 : w1;
    int8_t* wf = which ? wf2 : wf1;
    int o = (j >> 2) * 64 + (lane & 15) * 4 + (j & 3);
    int cbase = kh * 64 + (lane >> 4) * 16;
    int r = tap / 3, s = tap % 3;
    int8_t frag[16];
#pragma unroll
    for (int jj = 0; jj < 16; ++jj) {
        float f = w[((size_t)(o * C + cbase + jj) * 3 + r) * 3 + s];
        frag[jj] = (int8_t)((f > 0.f) - (f < 0.f));
    }
    *(v4i*)(wf + (size_t)(((tap * 2 + kh) * 8 + j) * 64 + lane) * 16) =
        *(const v4i*)frag;
}

// ---------------------------------------------------------------------------
// Persistent binary conv. Grid = 256 blocks (1/CU, LDS-limited), 512 thr =
// 8 waves = 4 row-quarters x 2 O-halves. Wave = 64 rows x 64 O:
// acc[4][4] = 64 VGPRs, per step 4 ds_read_b128 + 16 MFMA + 4 A-prefetch.
// K-loop unroll 1 (prevents cross-step load hoisting -> spills, see R6).
// All 18*8KB weights staged to LDS once; XCD-swizzled static tile schedule.
// PHASE 1: sign(BN1(conv)) -> padded NHWC int8 (4 contiguous bytes/lane).
// PHASE 2: clip(BN2(conv) + residual, -1, 1) -> NCHW fp32 (float4 I/O).
template <int PHASE>
__global__ __launch_bounds__(512, 1) void conv_bin(
    const int8_t* __restrict__ xs,
    const int8_t* __restrict__ wf,
    const float* __restrict__ bnp,
    const float* __restrict__ xres,
    int8_t* __restrict__ xs_next,
    float* __restrict__ out)
{
    __shared__ int8_t wlds[18 * 8192];       // 147,456 B (gfx950: 160K/WG)
    int t = threadIdx.x, lane = t & 63, wv = t >> 6;
    int quad = lane >> 4, l15 = lane & 15;
    int wrow  = wv & 3;                      // row-quarter (64 rows)
    int whalf = wv >> 2;                     // O-half (64 channels)

    // one-time weight staging
    {
        const v4i* g = (const v4i*)wf;
        v4i* l = (v4i*)wlds;
        for (int i = t; i < 18 * 512; i += 512) l[i] = g[i];
    }
    // BN params for this lane's 4 contiguous channels o = whalf*64 + l15*4 + nl
    float binv[4], btt[4];
    int obase = whalf * 64 + l15 * 4;
    {
        int o0 = (PHASE == 1 ? 0 : 256) + obase;
        int o1 = (PHASE == 1 ? 128 : 384) + obase;
#pragma unroll
        for (int nl = 0; nl < 4; ++nl) { binv[nl] = bnp[o0 + nl]; btt[nl] = bnp[o1 + nl]; }
    }
    __syncthreads();

    int xcd = blockIdx.x & 7, local = blockIdx.x >> 3;   // 32 blocks per XCD
#pragma unroll 1
    for (int tloc = local; tloc < TPX; tloc += 32) {
        int tile = xcd * TPX + tloc;
        int mwave = tile * 256 + wrow * 64;
        int abase[4];
#pragma unroll
        for (int rg = 0; rg < 4; ++rg) {
            int ma = mwave + rg * 16 + l15;
            int wa = ma % W; int ta = ma / W; int ha = ta % H; int ba = ta / H;
            abase[rg] = ((ba * HP + ha) * WP + wa) * C + quad * 16;
        }

        v4i acc[4][4];
#pragma unroll
        for (int rg = 0; rg < 4; ++rg)
#pragma unroll
            for (int nl = 0; nl < 4; ++nl) acc[rg][nl] = (v4i)0;

        v4i a[4];
#pragma unroll
        for (int rg = 0; rg < 4; ++rg) a[rg] = *(const v4i*)(xs + abase[rg]);

#pragma unroll 1   // DO NOT fully unroll: cross-step load hoisting -> spills
        for (int step = 0; step < 18; ++step) {
            v4i an[4];
            if (step + 1 < 18) {
                int nt = (step + 1) >> 1, nk = (step + 1) & 1;
                int aoff = ((nt / 3) * WP + (nt % 3)) * C + nk * 64;
#pragma unroll
                for (int rg = 0; rg < 4; ++rg)
                    an[rg] = *(const v4i*)(xs + abase[rg] + aoff);
            }
            const int8_t* lb = wlds + step * 8192 + whalf * 4096;
#pragma unroll
            for (int nl = 0; nl < 4; ++nl) {
                v4i bf = *(const v4i*)(lb + ((nl * 64 + lane) << 4));
#pragma unroll
                for (int rg = 0; rg < 4; ++rg)
                    acc[rg][nl] = __builtin_amdgcn_mfma_i32_16x16x64_i8(
                        a[rg], bf, acc[rg][nl], 0, 0, 0);
            }
#pragma unroll
            for (int rg = 0; rg < 4; ++rg) a[rg] = an[rg];
        }

        // Epilogue. D layout: col = l15 (-> o = obase+nl), row = quad*4 + i.
#pragma unroll
        for (int rg = 0; rg < 4; ++rg) {
            int m0 = mwave + rg * 16 + quad * 4;     // multiple of 4; W%4==0
            int w0 = m0 % W; int t0 = m0 / W; int h0 = t0 % H; int b0 = t0 / H;
            if (PHASE == 1) {
                int base = ((b0 * HP + h0 + 1) * WP + (w0 + 1)) * C + obase;
#pragma unroll
                for (int i = 0; i < 4; ++i) {
                    uint32_t pk = 0;
#pragma unroll
                    for (int nl = 0; nl < 4; ++nl) {
                        float y = __fadd_rn(__fmul_rn((float)acc[rg][nl][i], binv[nl]), btt[nl]);
                        pk |= ((uint32_t)(uint8_t)(int8_t)((y > 0.f) - (y < 0.f))) << (8 * nl);
                    }
                    *(uint32_t*)(xs_next + base + i * C) = pk;
                }
            } else {
                int pixb = b0 * C * PIX + h0 * W + w0;
#pragma unroll
                for (int nl = 0; nl < 4; ++nl) {
                    int idx = pixb + (obase + nl) * PIX;
                    v4f r = *(const v4f*)(xres + idx);
                    v4f z;
#pragma unroll
                    for (int i = 0; i < 4; ++i) {
                        float y = __fadd_rn(__fmul_rn((float)acc[rg][nl][i], binv[nl]), btt[nl]);
                        float v = __fadd_rn(y, r[i]);
                        z[i] = fminf(fmaxf(v, -1.f), 1.f);
                    }
                    *(v4f*)(out + idx) = z;
                }
            }
        }
    }
}

// ---------------------------------------------------------------------------
extern "C" void kernel_launch(void* const* d_in, const int* in_sizes, int n_in,
                              void* d_out, int out_size, void* d_ws, size_t ws_size,
                              hipStream_t stream) {
    const float* x   = (const float*)d_in[0];
    const float* w1  = (const float*)d_in[1];
    const float* w2  = (const float*)d_in[2];
    const float* g1  = (const float*)d_in[3];
    const float* be1 = (const float*)d_in[4];
    const float* mu1 = (const float*)d_in[5];
    const float* va1 = (const float*)d_in[6];
    const float* g2  = (const float*)d_in[7];
    const float* be2 = (const float*)d_in[8];
    const float* mu2 = (const float*)d_in[9];
    const float* va2 = (const float*)d_in[10];

    int8_t* ws  = (int8_t*)d_ws;
    int8_t* xs1 = ws + XS1_OFF;
    int8_t* xs2 = ws + XS2_OFF;
    int8_t* wf1 = ws + WF1_OFF;
    int8_t* wf2 = ws + WF2_OFF;
    float*  bnp = (float*)(ws + BNP_OFF);

    zero_halo<<<256, 256, 0, stream>>>(xs1, xs2);
    prep_x<<<M / 256, 256, 0, stream>>>(x, xs1);
    prep_w<<<(2 * 18 * 8 * 64 + 255) / 256, 256, 0, stream>>>(
        w1, w2, g1, be1, mu1, va1, g2, be2, mu2, va2, wf1, wf2, bnp);

    conv_bin<1><<<256, 512, 0, stream>>>(xs1, wf1, bnp, nullptr, xs2, nullptr);
    conv_bin<2><<<256, 512, 0, stream>>>(xs2, wf2, bnp, x, nullptr, (float*)d_out);
}

// Round 8
// 394.622 us; speedup vs baseline: 1.0062x; 1.0062x over previous
//
#include <hip/hip_runtime.h>
#include <cstdint>
#include <cstddef>

// Binarized basic block on MI355X.
// |acc| <= 9*128 = 1152 < THRESH=8000, so the per-partial-sum clip never
// binds -> both convs are exact int convolutions of sign() values.
// int8 implicit GEMM via mfma_i32_16x16x64_i8; all float ops bit-exact vs
// numpy fp32 (explicit __fmul_rn/__fadd_rn, no FMA contraction).
//
// R8: R6/R7 showed the K-loop is LATENCY-bound (MfmaUtil ~11%, occupancy
// ~17%, no pipe saturated): the per-step A-load/ds_read chain isn't covered
// by 2 waves/SIMD. Fix: 1024-thr blocks -> 16 waves = 4 waves/SIMD
// (8 row-groups x 2 O-halves; wave = 32 rows x 64 O, acc[2][4]=32 VGPRs,
// fits the 128-reg budget 4 waves/SIMD requires), PLUS B-frag prefetch one
// step ahead (bf ring) alongside the A-prefetch, PLUS non-temporal loads
// for streamed fp32 (x, residual) to keep xs in L2. Weights stay fully
// LDS-resident (144 KB); unroll-1 K-loop (R6 spill fix); XCD-local tiles.

typedef int      v4i __attribute__((ext_vector_type(4)));
typedef float    v4f __attribute__((ext_vector_type(4)));

constexpr int B = 64, C = 128, H = 56, W = 56;
constexpr int HP = H + 2, WP = W + 2;      // zero-padded spatial
constexpr int PIX = H * W;                 // 3136
constexpr int M = B * H * W;               // 200704 = 784 * 256
constexpr int NTILES = M / 256;            // 784 tiles of 256 rows
constexpr int TPX = NTILES / 8;            // 98 tiles per XCD

// workspace layout (bytes)
constexpr size_t XS_BYTES = (size_t)B * HP * WP * C;   // 27,557,888
constexpr size_t XS1_OFF = 0;
constexpr size_t XS2_OFF = XS_BYTES;
constexpr size_t WF_BYTES = 18 * 8192;                 // 147,456
constexpr size_t WF1_OFF = 2 * XS_BYTES;
constexpr size_t WF2_OFF = WF1_OFF + WF_BYTES;
constexpr size_t BNP_OFF = WF2_OFF + WF_BYTES;         // 4*128 floats

// ---------------------------------------------------------------------------
// Zero only the padded halos of xs1/xs2 (interiors are fully overwritten).
// 256 blocks: 4 blocks per image.
__global__ __launch_bounds__(256) void zero_halo(int8_t* __restrict__ xs1,
                                                 int8_t* __restrict__ xs2) {
    int b = blockIdx.x >> 2;
    int q = blockIdx.x & 3;
    int t = q * 256 + threadIdx.x;           // 0..1023
    size_t ib = (size_t)b * HP * WP * C;
#pragma unroll
    for (int a = 0; a < 2; ++a) {
        uint32_t* p = (uint32_t*)((a ? xs2 : xs1) + ib);
        const int ROWD = WP * C / 4;             // 1856 dwords per padded row
        for (int i = t; i < ROWD; i += 1024) {
            p[i] = 0;
            p[(HP - 1) * ROWD + i] = 0;
        }
        for (int i = t; i < 56 * 2 * 32; i += 1024) {
            int r = i >> 6;
            int side = (i >> 5) & 1;
            int j = i & 31;
            p[((r + 1) * WP + side * (WP - 1)) * (C / 4) + j] = 0;
        }
    }
}

// ---------------------------------------------------------------------------
// sign(x) -> padded NHWC int8, via LDS transpose so global stores are
// 16 B/lane full-line. Block = 256 threads = 256 pixels. NT loads keep x
// from polluting L2.
__global__ __launch_bounds__(256) void prep_x(const float* __restrict__ x,
                                              int8_t* __restrict__ xs) {
    __shared__ uint32_t tl[256 * 33];   // +1 dword pad -> conflict-free
    int t = threadIdx.x;
    int m = blockIdx.x * 256 + t;
    int b_ = m / PIX, hw = m % PIX;
    const float* xp = x + (size_t)b_ * C * PIX + hw;
#pragma unroll
    for (int c4 = 0; c4 < 32; ++c4) {
        uint32_t v = 0;
#pragma unroll
        for (int j = 0; j < 4; ++j) {
            float f = __builtin_nontemporal_load(xp + (size_t)(c4 * 4 + j) * PIX);
            v |= ((uint32_t)(uint8_t)(int8_t)((f > 0.f) - (f < 0.f))) << (8 * j);
        }
        tl[t * 33 + c4] = v;
    }
    __syncthreads();
    int pl = t >> 3, co = t & 7;        // 8 threads per pixel, 16 B each
#pragma unroll
    for (int pass = 0; pass < 8; ++pass) {
        int p = pass * 32 + pl;
        int mg = blockIdx.x * 256 + p;
        int b2 = mg / PIX, hw2 = mg % PIX, h2 = hw2 / W, w2 = hw2 % W;
        size_t ob = ((size_t)(b2 * HP + h2 + 1) * WP + (w2 + 1)) * C + co * 16;
        v4i val;
#pragma unroll
        for (int k = 0; k < 4; ++k) val[k] = (int)tl[p * 33 + co * 4 + k];
        *(v4i*)(xs + ob) = val;
    }
}

// ---------------------------------------------------------------------------
// Binarize weights into MFMA B-fragment order. Fragment tile j (0..7, 16 O
// each) at LDS offset j*1024; column col=lane&15 maps to output channel
//   o = (j>>2)*64 + (lane&15)*4 + (j&3)
// so a wave owning O-half (j>>2) with sub-tile nl=(j&3) gives each lane 4
// CONTIGUOUS channels. Also BN inv/shift tables exactly as numpy fp32.
__global__ __launch_bounds__(256) void prep_w(
    const float* __restrict__ w1, const float* __restrict__ w2,
    const float* __restrict__ g1, const float* __restrict__ be1,
    const float* __restrict__ mu1, const float* __restrict__ va1,
    const float* __restrict__ g2, const float* __restrict__ be2,
    const float* __restrict__ mu2, const float* __restrict__ va2,
    int8_t* __restrict__ wf1, int8_t* __restrict__ wf2,
    float* __restrict__ bnp) {
    int t = blockIdx.x * 256 + threadIdx.x;
    if (t < 256) {
        int o = t & 127;
        if (t < 128) {
            float inv = g1[o] / sqrtf(va1[o] + 1e-5f);
            bnp[o]       = inv;
            bnp[128 + o] = __fsub_rn(be1[o], __fmul_rn(mu1[o], inv));
        } else {
            float inv = g2[o] / sqrtf(va2[o] + 1e-5f);
            bnp[256 + o] = inv;
            bnp[384 + o] = __fsub_rn(be2[o], __fmul_rn(mu2[o], inv));
        }
    }
    if (t >= 2 * 18 * 8 * 64) return;
    int lane = t & 63;
    int j    = (t >> 6) & 7;
    int kh   = (t >> 9) & 1;
    int tap  = (t >> 10) % 9;
    int which = (t >> 10) / 9;
    const float* w = which ? w2 : w1;
    int8_t* wf = which ? wf2 : wf1;
    int o = (j >> 2) * 64 + (lane & 15) * 4 + (j & 3);
    int cbase = kh * 64 + (lane >> 4) * 16;
    int r = tap / 3, s = tap % 3;
    int8_t frag[16];
#pragma unroll
    for (int jj = 0; jj < 16; ++jj) {
        float f = w[((size_t)(o * C + cbase + jj) * 3 + r) * 3 + s];
        frag[jj] = (int8_t)((f > 0.f) - (f < 0.f));
    }
    *(v4i*)(wf + (size_t)(((tap * 2 + kh) * 8 + j) * 64 + lane) * 16) =
        *(const v4i*)frag;
}

// ---------------------------------------------------------------------------
// Persistent binary conv. Grid = 256 blocks (1/CU, LDS-limited), 1024 thr =
// 16 waves = 4 waves/SIMD = 8 row-groups x 2 O-halves. Wave = 32 rows x 64 O:
// acc[2][4] = 32 VGPRs (block forces <=128 VGPR for 4 waves/SIMD; est ~110).
// All 18*8KB weights staged to LDS once; XCD-swizzled static tile schedule.
// K-loop unroll 1 (R6: full unroll hoists all prefetches -> spills).
// Per step per wave: 2 A-prefetch global loads (step+1), 4 ds_read_b128
// B-prefetch (step+1), 8 MFMAs on current regs. Both prefetches get a full
// ~650-cyc step of slack; 4 waves/SIMD interleave to fill the MFMA pipe.
// PHASE 1: sign(BN1(conv)) -> padded NHWC int8 (4 contiguous bytes/lane).
// PHASE 2: clip(BN2(conv) + residual, -1, 1) -> NCHW fp32 (float4 I/O,
//          NT residual loads keep xs2 L2-resident).
template <int PHASE>
__global__ __launch_bounds__(1024, 1) void conv_bin(
    const int8_t* __restrict__ xs,
    const int8_t* __restrict__ wf,
    const float* __restrict__ bnp,
    const float* __restrict__ xres,
    int8_t* __restrict__ xs_next,
    float* __restrict__ out)
{
    __shared__ int8_t wlds[18 * 8192];       // 147,456 B (gfx950: 160K/WG)
    int t = threadIdx.x, lane = t & 63, wv = t >> 6;
    int quad = lane >> 4, l15 = lane & 15;
    int wrow  = wv & 7;                      // row-group (32 rows)
    int whalf = wv >> 3;                     // O-half (64 channels)

    // one-time weight staging
    {
        const v4i* g = (const v4i*)wf;
        v4i* l = (v4i*)wlds;
        for (int i = t; i < 18 * 512; i += 1024) l[i] = g[i];
    }
    // BN params for this lane's 4 contiguous channels o = whalf*64 + l15*4 + nl
    float binv[4], btt[4];
    int obase = whalf * 64 + l15 * 4;
    {
        int o0 = (PHASE == 1 ? 0 : 256) + obase;
        int o1 = (PHASE == 1 ? 128 : 384) + obase;
#pragma unroll
        for (int nl = 0; nl < 4; ++nl) { binv[nl] = bnp[o0 + nl]; btt[nl] = bnp[o1 + nl]; }
    }
    __syncthreads();

    int xcd = blockIdx.x & 7, local = blockIdx.x >> 3;   // 32 blocks per XCD
#pragma unroll 1
    for (int tloc = local; tloc < TPX; tloc += 32) {
        int tile = xcd * TPX + tloc;
        int mwave = tile * 256 + wrow * 32;
        int abase[2];
#pragma unroll
        for (int rg = 0; rg < 2; ++rg) {
            int ma = mwave + rg * 16 + l15;
            int wa = ma % W; int ta = ma / W; int ha = ta % H; int ba = ta / H;
            abase[rg] = ((ba * HP + ha) * WP + wa) * C + quad * 16;
        }

        v4i acc[2][4];
#pragma unroll
        for (int rg = 0; rg < 2; ++rg)
#pragma unroll
            for (int nl = 0; nl < 4; ++nl) acc[rg][nl] = (v4i)0;

        // step-0 operands
        v4i a[2], bf[4];
#pragma unroll
        for (int rg = 0; rg < 2; ++rg) a[rg] = *(const v4i*)(xs + abase[rg]);
        {
            const int8_t* lb = wlds + whalf * 4096;
#pragma unroll
            for (int nl = 0; nl < 4; ++nl)
                bf[nl] = *(const v4i*)(lb + ((nl * 64 + lane) << 4));
        }

#pragma unroll 1   // DO NOT fully unroll: cross-step load hoisting -> spills
        for (int step = 0; step < 18; ++step) {
            v4i an[2], bfn[4];
            if (step + 1 < 18) {
                int nt_ = (step + 1) >> 1, nk = (step + 1) & 1;
                int aoff = ((nt_ / 3) * WP + (nt_ % 3)) * C + nk * 64;
#pragma unroll
                for (int rg = 0; rg < 2; ++rg)
                    an[rg] = *(const v4i*)(xs + abase[rg] + aoff);
                const int8_t* lbn = wlds + (step + 1) * 8192 + whalf * 4096;
#pragma unroll
                for (int nl = 0; nl < 4; ++nl)
                    bfn[nl] = *(const v4i*)(lbn + ((nl * 64 + lane) << 4));
            }
#pragma unroll
            for (int nl = 0; nl < 4; ++nl)
#pragma unroll
                for (int rg = 0; rg < 2; ++rg)
                    acc[rg][nl] = __builtin_amdgcn_mfma_i32_16x16x64_i8(
                        a[rg], bf[nl], acc[rg][nl], 0, 0, 0);
            if (step + 1 < 18) {
#pragma unroll
                for (int rg = 0; rg < 2; ++rg) a[rg] = an[rg];
#pragma unroll
                for (int nl = 0; nl < 4; ++nl) bf[nl] = bfn[nl];
            }
        }

        // Epilogue. D layout: col = l15 (-> o = obase+nl), row = quad*4 + i.
#pragma unroll
        for (int rg = 0; rg < 2; ++rg) {
            int m0 = mwave + rg * 16 + quad * 4;     // multiple of 4; W%4==0
            int w0 = m0 % W; int t0 = m0 / W; int h0 = t0 % H; int b0 = t0 / H;
            if (PHASE == 1) {
                int base = ((b0 * HP + h0 + 1) * WP + (w0 + 1)) * C + obase;
#pragma unroll
                for (int i = 0; i < 4; ++i) {
                    uint32_t pk = 0;
#pragma unroll
                    for (int nl = 0; nl < 4; ++nl) {
                        float y = __fadd_rn(__fmul_rn((float)acc[rg][nl][i], binv[nl]), btt[nl]);
                        pk |= ((uint32_t)(uint8_t)(int8_t)((y > 0.f) - (y < 0.f))) << (8 * nl);
                    }
                    *(uint32_t*)(xs_next + base + i * C) = pk;
                }
            } else {
                int pixb = b0 * C * PIX + h0 * W + w0;
#pragma unroll
                for (int nl = 0; nl < 4; ++nl) {
                    int idx = pixb + (obase + nl) * PIX;
                    v4f r = __builtin_nontemporal_load((const v4f*)(xres + idx));
                    v4f z;
#pragma unroll
                    for (int i = 0; i < 4; ++i) {
                        float y = __fadd_rn(__fmul_rn((float)acc[rg][nl][i], binv[nl]), btt[nl]);
                        float v = __fadd_rn(y, r[i]);
                        z[i] = fminf(fmaxf(v, -1.f), 1.f);
                    }
                    *(v4f*)(out + idx) = z;
                }
            }
        }
    }
}

// ---------------------------------------------------------------------------
extern "C" void kernel_launch(void* const* d_in, const int* in_sizes, int n_in,
                              void* d_out, int out_size, void* d_ws, size_t ws_size,
                              hipStream_t stream) {
    const float* x   = (const float*)d_in[0];
    const float* w1  = (const float*)d_in[1];
    const float* w2  = (const float*)d_in[2];
    const float* g1  = (const float*)d_in[3];
    const float* be1 = (const float*)d_in[4];
    const float* mu1 = (const float*)d_in[5];
    const float* va1 = (const float*)d_in[6];
    const float* g2  = (const float*)d_in[7];
    const float* be2 = (const float*)d_in[8];
    const float* mu2 = (const float*)d_in[9];
    const float* va2 = (const float*)d_in[10];

    int8_t* ws  = (int8_t*)d_ws;
    int8_t* xs1 = ws + XS1_OFF;
    int8_t* xs2 = ws + XS2_OFF;
    int8_t* wf1 = ws + WF1_OFF;
    int8_t* wf2 = ws + WF2_OFF;
    float*  bnp = (float*)(ws + BNP_OFF);

    zero_halo<<<256, 256, 0, stream>>>(xs1, xs2);
    prep_x<<<M / 256, 256, 0, stream>>>(x, xs1);
    prep_w<<<(2 * 18 * 8 * 64 + 255) / 256, 256, 0, stream>>>(
        w1, w2, g1, be1, mu1, va1, g2, be2, mu2, va2, wf1, wf2, bnp);

    conv_bin<1><<<256, 1024, 0, stream>>>(xs1, wf1, bnp, nullptr, xs2, nullptr);
    conv_bin<2><<<256, 1024, 0, stream>>>(xs2, wf2, bnp, x, nullptr, (float*)d_out);
}

// Round 9
// 327.022 us; speedup vs baseline: 1.2141x; 1.2067x over previous
//
#include <hip/hip_runtime.h>
#include <cstdint>
#include <cstddef>

// Binarized basic block on MI355X.
// |acc| <= 9*128 = 1152 < THRESH=8000 -> the per-partial-sum clip never binds
// -> both convs are exact int convolutions of sign() values. int8 implicit
// GEMM via mfma_i32_16x16x64_i8; float ops bit-exact vs numpy fp32.
//
// R9 (on R6 base: 8 waves x 32 rows x 128 O, weights fully LDS-resident,
// contiguous-O stores, XCD-local tiles):
//  1. K-step order (r, kh, s): s-adjacent steps are distance-1 -> the 15/16
//     line overlap between taps (r,s)/(r,s+1) hits L1 (16 KB/step/CU reuse
//     distance < 32 KB L1). R6-R8 used s-distance-2 -> L2/L3 thrash
//     (FETCH 87 MB vs 27.5 MB ideal).
//  2. Manual ping-pong 2x unroll (two register sets, NO a=an copies): R6-R8's
//     copies forced vmcnt(0)/lgkmcnt(0) drains inside the same step. Now each
//     prefetch has a full 16-MFMA block of slack and waits are per-set.
//  3. Tail fix: 96 tiles/XCD = 3 exact rounds of 32 blocks; the 2 leftover
//     tiles/XCD run as 4 half-tiles (RG=1) on 4 blocks -> wall 3.5 rounds
//     instead of 4 (R6-R8 lost ~30% to the 3.06-round static schedule).

typedef int      v4i __attribute__((ext_vector_type(4)));
typedef float    v4f __attribute__((ext_vector_type(4)));
typedef unsigned int v2u __attribute__((ext_vector_type(2)));

constexpr int B = 64, C = 128, H = 56, W = 56;
constexpr int HP = H + 2, WP = W + 2;      // zero-padded spatial
constexpr int PIX = H * W;                 // 3136
constexpr int M = B * H * W;               // 200704 = 784 * 256
constexpr int NTILES = M / 256;            // 784 tiles of 256 rows
constexpr int TPX = NTILES / 8;            // 98 tiles per XCD

// workspace layout (bytes)
constexpr size_t XS_BYTES = (size_t)B * HP * WP * C;   // 27,557,888
constexpr size_t XS1_OFF = 0;
constexpr size_t XS2_OFF = XS_BYTES;
constexpr size_t WF_BYTES = 18 * 8192;                 // 147,456
constexpr size_t WF1_OFF = 2 * XS_BYTES;
constexpr size_t WF2_OFF = WF1_OFF + WF_BYTES;
constexpr size_t BNP_OFF = WF2_OFF + WF_BYTES;         // 4*128 floats

// step = r*6 + kh*3 + s  (r = step/6, kh = (step/3)&1, s = step%3)
__device__ __forceinline__ int step_aoff(int st) {
    int r = st / 6, kh = (st / 3) & 1, s = st % 3;
    return (r * WP + s) * C + kh * 64;
}

// ---------------------------------------------------------------------------
// Zero only the padded halos of xs1/xs2. 256 blocks: 4 per image.
__global__ __launch_bounds__(256) void zero_halo(int8_t* __restrict__ xs1,
                                                 int8_t* __restrict__ xs2) {
    int b = blockIdx.x >> 2;
    int q = blockIdx.x & 3;
    int t = q * 256 + threadIdx.x;           // 0..1023
    size_t ib = (size_t)b * HP * WP * C;
#pragma unroll
    for (int a = 0; a < 2; ++a) {
        uint32_t* p = (uint32_t*)((a ? xs2 : xs1) + ib);
        const int ROWD = WP * C / 4;             // 1856 dwords per padded row
        for (int i = t; i < ROWD; i += 1024) {
            p[i] = 0;
            p[(HP - 1) * ROWD + i] = 0;
        }
        for (int i = t; i < 56 * 2 * 32; i += 1024) {
            int r = i >> 6;
            int side = (i >> 5) & 1;
            int j = i & 31;
            p[((r + 1) * WP + side * (WP - 1)) * (C / 4) + j] = 0;
        }
    }
}

// ---------------------------------------------------------------------------
// sign(x) -> padded NHWC int8 via LDS transpose (16 B/lane full-line stores).
__global__ __launch_bounds__(256) void prep_x(const float* __restrict__ x,
                                              int8_t* __restrict__ xs) {
    __shared__ uint32_t tl[256 * 33];
    int t = threadIdx.x;
    int m = blockIdx.x * 256 + t;
    int b_ = m / PIX, hw = m % PIX;
    const float* xp = x + (size_t)b_ * C * PIX + hw;
#pragma unroll
    for (int c4 = 0; c4 < 32; ++c4) {
        uint32_t v = 0;
#pragma unroll
        for (int j = 0; j < 4; ++j) {
            float f = __builtin_nontemporal_load(xp + (size_t)(c4 * 4 + j) * PIX);
            v |= ((uint32_t)(uint8_t)(int8_t)((f > 0.f) - (f < 0.f))) << (8 * j);
        }
        tl[t * 33 + c4] = v;
    }
    __syncthreads();
    int pl = t >> 3, co = t & 7;
#pragma unroll
    for (int pass = 0; pass < 8; ++pass) {
        int p = pass * 32 + pl;
        int mg = blockIdx.x * 256 + p;
        int b2 = mg / PIX, hw2 = mg % PIX, h2 = hw2 / W, w2 = hw2 % W;
        size_t ob = ((size_t)(b2 * HP + h2 + 1) * WP + (w2 + 1)) * C + co * 16;
        v4i val;
#pragma unroll
        for (int k = 0; k < 4; ++k) val[k] = (int)tl[p * 33 + co * 4 + k];
        *(v4i*)(xs + ob) = val;
    }
}

// ---------------------------------------------------------------------------
// Binarize weights into MFMA B-fragment order, slot = r*6 + kh*3 + s, with
// o = (lane&15)*8 + n (lane-contiguous O). BN tables exactly numpy fp32.
__global__ __launch_bounds__(256) void prep_w(
    const float* __restrict__ w1, const float* __restrict__ w2,
    const float* __restrict__ g1, const float* __restrict__ be1,
    const float* __restrict__ mu1, const float* __restrict__ va1,
    const float* __restrict__ g2, const float* __restrict__ be2,
    const float* __restrict__ mu2, const float* __restrict__ va2,
    int8_t* __restrict__ wf1, int8_t* __restrict__ wf2,
    float* __restrict__ bnp) {
    int t = blockIdx.x * 256 + threadIdx.x;
    if (t < 256) {
        int o = t & 127;
        if (t < 128) {
            float inv = g1[o] / sqrtf(va1[o] + 1e-5f);
            bnp[o]       = inv;
            bnp[128 + o] = __fsub_rn(be1[o], __fmul_rn(mu1[o], inv));
        } else {
            float inv = g2[o] / sqrtf(va2[o] + 1e-5f);
            bnp[256 + o] = inv;
            bnp[384 + o] = __fsub_rn(be2[o], __fmul_rn(mu2[o], inv));
        }
    }
    if (t >= 2 * 18 * 8 * 64) return;
    int lane = t & 63;
    int nsub = (t >> 6) & 7;
    int kh   = (t >> 9) & 1;
    int tap  = (t >> 10) % 9;
    int which = (t >> 10) / 9;
    const float* w = which ? w2 : w1;
    int8_t* wf = which ? wf2 : wf1;
    int o = (lane & 15) * 8 + nsub;
    int cbase = kh * 64 + (lane >> 4) * 16;
    int r = tap / 3, s = tap % 3;
    int slot = r * 6 + kh * 3 + s;           // R9: (r, kh, s) step order
    int8_t frag[16];
#pragma unroll
    for (int j = 0; j < 16; ++j) {
        float f = w[((size_t)(o * C + cbase + j) * 3 + r) * 3 + s];
        frag[j] = (int8_t)((f > 0.f) - (f < 0.f));
    }
    *(v4i*)(wf + (size_t)((slot * 8 + nsub) * 64 + lane) * 16) =
        *(const v4i*)frag;
}

// ---------------------------------------------------------------------------
// One tile's worth of conv for one wave: RG row-groups x all 128 O.
// Ping-pong 2x unrolled K-loop, no register copies.
template <int PHASE, int RG>
__device__ __forceinline__ void do_tile(
    int mwave, const int8_t* __restrict__ xs, const int8_t* wlds,
    const float* binv, const float* btt, int lane, int quad, int l15,
    const float* __restrict__ xres, int8_t* __restrict__ xs_next,
    float* __restrict__ out)
{
    int abase[RG];
#pragma unroll
    for (int rg = 0; rg < RG; ++rg) {
        int ma = mwave + rg * 16 + l15;
        int wa = ma % W; int ta = ma / W; int ha = ta % H; int ba = ta / H;
        abase[rg] = ((ba * HP + ha) * WP + wa) * C + quad * 16;
    }

    v4i acc[RG][8];
#pragma unroll
    for (int rg = 0; rg < RG; ++rg)
#pragma unroll
        for (int n = 0; n < 8; ++n) acc[rg][n] = (v4i)0;

    v4i a0[RG], a1[RG], bf0[8], bf1[8];
    // prologue: set0 <- step 0 (aoff = 0)
#pragma unroll
    for (int rg = 0; rg < RG; ++rg) a0[rg] = *(const v4i*)(xs + abase[rg]);
#pragma unroll
    for (int n = 0; n < 8; ++n)
        bf0[n] = *(const v4i*)(wlds + ((n * 64 + lane) << 4));

#pragma unroll 1   // keep rolled: full unroll hoists prefetches -> spills (R5)
    for (int s2 = 0; s2 < 18; s2 += 2) {
        // prefetch set1 <- step s2+1
        {
            int aoff = step_aoff(s2 + 1);
            const int8_t* lb = wlds + (s2 + 1) * 8192;
#pragma unroll
            for (int rg = 0; rg < RG; ++rg)
                a1[rg] = *(const v4i*)(xs + abase[rg] + aoff);
#pragma unroll
            for (int n = 0; n < 8; ++n)
                bf1[n] = *(const v4i*)(lb + ((n * 64 + lane) << 4));
        }
        // MFMA on set0 (loaded >= one half-step ago)
#pragma unroll
        for (int n = 0; n < 8; ++n)
#pragma unroll
            for (int rg = 0; rg < RG; ++rg)
                acc[rg][n] = __builtin_amdgcn_mfma_i32_16x16x64_i8(
                    a0[rg], bf0[n], acc[rg][n], 0, 0, 0);
        // prefetch set0 <- step s2+2
        if (s2 + 2 < 18) {
            int aoff = step_aoff(s2 + 2);
            const int8_t* lb = wlds + (s2 + 2) * 8192;
#pragma unroll
            for (int rg = 0; rg < RG; ++rg)
                a0[rg] = *(const v4i*)(xs + abase[rg] + aoff);
#pragma unroll
            for (int n = 0; n < 8; ++n)
                bf0[n] = *(const v4i*)(lb + ((n * 64 + lane) << 4));
        }
        // MFMA on set1
#pragma unroll
        for (int n = 0; n < 8; ++n)
#pragma unroll
            for (int rg = 0; rg < RG; ++rg)
                acc[rg][n] = __builtin_amdgcn_mfma_i32_16x16x64_i8(
                    a1[rg], bf1[n], acc[rg][n], 0, 0, 0);
    }

    // Epilogue. D layout: col = l15 (-> o = l15*8 + n), row = quad*4 + i.
#pragma unroll
    for (int rg = 0; rg < RG; ++rg) {
        int m0 = mwave + rg * 16 + quad * 4;         // multiple of 4; W%4==0
        int w0 = m0 % W; int t0 = m0 / W; int h0 = t0 % H; int b0 = t0 / H;
        if (PHASE == 1) {
            int base = ((b0 * HP + h0 + 1) * WP + (w0 + 1)) * C + l15 * 8;
#pragma unroll
            for (int i = 0; i < 4; ++i) {
                uint32_t lo = 0, hi = 0;
#pragma unroll
                for (int n = 0; n < 8; ++n) {
                    float y = __fadd_rn(__fmul_rn((float)acc[rg][n][i], binv[n]), btt[n]);
                    uint32_t sb = (uint8_t)(int8_t)((y > 0.f) - (y < 0.f));
                    if (n < 4) lo |= sb << (8 * n);
                    else       hi |= sb << (8 * (n - 4));
                }
                v2u pk; pk[0] = lo; pk[1] = hi;
                *(v2u*)(xs_next + base + i * C) = pk;
            }
        } else {
            int pixb = b0 * C * PIX + h0 * W + w0;
#pragma unroll
            for (int n = 0; n < 8; ++n) {
                int idx = pixb + (l15 * 8 + n) * PIX;
                v4f r = __builtin_nontemporal_load((const v4f*)(xres + idx));
                v4f z;
#pragma unroll
                for (int i = 0; i < 4; ++i) {
                    float y = __fadd_rn(__fmul_rn((float)acc[rg][n][i], binv[n]), btt[n]);
                    float v = __fadd_rn(y, r[i]);
                    z[i] = fminf(fmaxf(v, -1.f), 1.f);
                }
                __builtin_nontemporal_store(z, (v4f*)(out + idx));
            }
        }
    }
}

// ---------------------------------------------------------------------------
// Persistent binary conv. Grid = 256 blocks (1/CU, LDS-limited), 512 thr =
// 8 waves (2/SIMD). Wave = 32 rows x 128 O (acc[2][8]).
// Schedule per XCD (xcd = bid&7, 32 blocks): 3 exact rounds over tiles
// [xcd*98, xcd*98+96), then the 2 leftover tiles as 4 half-tiles (RG=1,
// 16 rows/wave) on blocks local<4.
template <int PHASE>
__global__ __launch_bounds__(512, 1) void conv_bin(
    const int8_t* __restrict__ xs,
    const int8_t* __restrict__ wf,
    const float* __restrict__ bnp,
    const float* __restrict__ xres,
    int8_t* __restrict__ xs_next,
    float* __restrict__ out)
{
    __shared__ int8_t wlds[18 * 8192];       // 147,456 B
    int t = threadIdx.x, lane = t & 63, wv = t >> 6;
    int quad = lane >> 4, l15 = lane & 15;

    // one-time weight staging
    {
        const v4i* g = (const v4i*)wf;
        v4i* l = (v4i*)wlds;
        for (int i = t; i < 18 * 512; i += 512) l[i] = g[i];
    }
    float binv[8], btt[8];
    {
        int o0 = (PHASE == 1 ? 0 : 256) + l15 * 8;
        int o1 = (PHASE == 1 ? 128 : 384) + l15 * 8;
#pragma unroll
        for (int n = 0; n < 8; ++n) { binv[n] = bnp[o0 + n]; btt[n] = bnp[o1 + n]; }
    }
    __syncthreads();

    int xcd = blockIdx.x & 7, local = blockIdx.x >> 3;   // 32 blocks per XCD
#pragma unroll 1
    for (int tloc = local; tloc < 96; tloc += 32) {      // exactly 3 rounds
        int tile = xcd * TPX + tloc;
        do_tile<PHASE, 2>(tile * 256 + wv * 32, xs, wlds, binv, btt,
                          lane, quad, l15, xres, xs_next, out);
    }
    if (local < 4) {                                     // tail: 2 tiles/XCD
        int tile = xcd * TPX + 96 + (local >> 1);
        int mw = tile * 256 + (local & 1) * 128 + wv * 16;
        do_tile<PHASE, 1>(mw, xs, wlds, binv, btt,
                          lane, quad, l15, xres, xs_next, out);
    }
}

// ---------------------------------------------------------------------------
extern "C" void kernel_launch(void* const* d_in, const int* in_sizes, int n_in,
                              void* d_out, int out_size, void* d_ws, size_t ws_size,
                              hipStream_t stream) {
    const float* x   = (const float*)d_in[0];
    const float* w1  = (const float*)d_in[1];
    const float* w2  = (const float*)d_in[2];
    const float* g1  = (const float*)d_in[3];
    const float* be1 = (const float*)d_in[4];
    const float* mu1 = (const float*)d_in[5];
    const float* va1 = (const float*)d_in[6];
    const float* g2  = (const float*)d_in[7];
    const float* be2 = (const float*)d_in[8];
    const float* mu2 = (const float*)d_in[9];
    const float* va2 = (const float*)d_in[10];

    int8_t* ws  = (int8_t*)d_ws;
    int8_t* xs1 = ws + XS1_OFF;
    int8_t* xs2 = ws + XS2_OFF;
    int8_t* wf1 = ws + WF1_OFF;
    int8_t* wf2 = ws + WF2_OFF;
    float*  bnp = (float*)(ws + BNP_OFF);

    zero_halo<<<256, 256, 0, stream>>>(xs1, xs2);
    prep_x<<<M / 256, 256, 0, stream>>>(x, xs1);
    prep_w<<<(2 * 18 * 8 * 64 + 255) / 256, 256, 0, stream>>>(
        w1, w2, g1, be1, mu1, va1, g2, be2, mu2, va2, wf1, wf2, bnp);

    conv_bin<1><<<256, 512, 0, stream>>>(xs1, wf1, bnp, nullptr, xs2, nullptr);
    conv_bin<2><<<256, 512, 0, stream>>>(xs2, wf2, bnp, x, nullptr, (float*)d_out);
}